// Round 14
// baseline (243.922 us; speedup 1.0000x reference)
//
#include <hip/hip_runtime.h>
#include <math.h>

#define TILEW 64
#define TILEH 32
#define HALO  5
#define IH    42     // TILEH + 2*HALO staged rows
#define SW    76     // sx/sy row stride (19*4; Stage-A writes wave-contiguous)
#define NG    19     // float4 col-groups per staged row
#define HBW   64     // hb row stride; Stage-C reads bank=j&31, 2-way (free)

__global__ void zero_kernel(float* ws) {
    ws[0] = 0.0f;                 // partial-sum accumulator
    ((unsigned*)ws)[1] = 0u;      // block completion counter
}

// Round-14 (final): r9 verbatim (best measured: kernel 123.4us) + fused
// finalize (validated absmax=0 in r1-r5; saves one ~7us launch).
// Session-converged structure:
//  - 64x32 tile, 512 threads, 79KB LDS -> 2 blocks/CU (16 waves).
//    Occupancy is capped here by Stage B's ~100-128 VGPR live set:
//    arg2>=5 spills (r1/r12); role-split spills (r10); deeper C spills
//    (r13). arg2=4 is the proven operating point.
//  - Stage A branchless ok?:0 (r4/r5: uniform branch serializes loads,
//    halves effective HBM BW).
//  - hb row-major [42][64] (r4: pair-packing -> 4-way bank conflict).
//  - barrier flow: sync; B; sync; A(c+1); C  (A||C overlap ~ noise but
//    harmless; keeps 6 barriers/block).
//  - fused tail: atomicAdd + completion counter; last block finalizes.
__global__ __launch_bounds__(512, 4) void ssim_kernel(
    const float* __restrict__ img1, const float* __restrict__ img2,
    const float* __restrict__ window, float* __restrict__ ws,
    float* __restrict__ out,
    int H, int W, float inv_n, unsigned nblocks)
{
    __shared__ float sx[IH][SW];
    __shared__ float sy[IH][SW];
    __shared__ float hb[5][IH][HBW];
    __shared__ float wsum[8];

    const int tid = threadIdx.x;
    const int x0  = blockIdx.x * TILEW;
    const int y0  = blockIdx.y * TILEH;

    // Recover the separable 1D Gaussian from the 2D window:
    // w2d = outer(g,g) -> g[j] = w2d[5][j] / sqrt(w2d[5][5])
    float gr[11];
    {
        float inv = 1.0f / sqrtf(window[60]);     // window[5*11+5]
        #pragma unroll
        for (int t = 0; t < 11; ++t) gr[t] = window[55 + t] * inv;
    }

    // Stage A: load zero-padded input tile for channel c into sx/sy.
    // Branchless; loads feed LDS stores in the same body, nothing persists.
    auto stage_a = [&](int c) {
        for (int item = tid; item < IH * NG; item += 512) {
            int r   = item / NG;
            int j4  = (item % NG) * 4;
            int gh  = y0 + r - HALO;
            int gx0 = x0 + j4 - HALO;
            bool rowok = ((unsigned)gh < (unsigned)H);
            float vx[4], vy[4];
            #pragma unroll
            for (int k = 0; k < 4; ++k) {
                int gx = gx0 + k;
                bool ok = rowok && ((unsigned)gx < (unsigned)W);
                long off = ((long)gh * W + gx) * 3 + c;   // HWC layout
                vx[k] = ok ? img1[off] : 0.0f;
                vy[k] = ok ? img2[off] : 0.0f;
            }
            *(float4*)&sx[r][j4] = make_float4(vx[0], vx[1], vx[2], vx[3]);
            *(float4*)&sy[r][j4] = make_float4(vy[0], vy[1], vy[2], vy[3]);
        }
    };

    float acc = 0.0f;

    stage_a(0);   // prologue: channel 0

    for (int c = 0; c < 3; ++c) {
        __syncthreads();   // sx/sy(c) visible; hb readers of prev channel done

        // ---------- Stage B: horizontal conv (5 quantities), 4 cols/thread ----------
        for (int item = tid; item < IH * 16; item += 512) {
            int r  = item >> 4;
            int j4 = (item & 15) * 4;
            float xv[16], yv[16];
            *(float4*)&xv[0]  = *(const float4*)&sx[r][j4];
            *(float4*)&xv[4]  = *(const float4*)&sx[r][j4 + 4];
            *(float4*)&xv[8]  = *(const float4*)&sx[r][j4 + 8];
            *(float4*)&xv[12] = *(const float4*)&sx[r][j4 + 12];
            *(float4*)&yv[0]  = *(const float4*)&sy[r][j4];
            *(float4*)&yv[4]  = *(const float4*)&sy[r][j4 + 4];
            *(float4*)&yv[8]  = *(const float4*)&sy[r][j4 + 8];
            *(float4*)&yv[12] = *(const float4*)&sy[r][j4 + 12];

            float xx[14], yy[14], xy[14];
            #pragma unroll
            for (int t = 0; t < 14; ++t) {
                xx[t] = xv[t] * xv[t];
                yy[t] = yv[t] * yv[t];
                xy[t] = xv[t] * yv[t];
            }
            float h0[4] = {0,0,0,0}, h1[4] = {0,0,0,0}, h2[4] = {0,0,0,0};
            float h3[4] = {0,0,0,0}, h4[4] = {0,0,0,0};
            #pragma unroll
            for (int jj = 0; jj < 4; ++jj) {
                #pragma unroll
                for (int t = 0; t < 11; ++t) {
                    float g = gr[t];
                    h0[jj] += g * xv[jj + t];
                    h1[jj] += g * yv[jj + t];
                    h2[jj] += g * xx[jj + t];
                    h3[jj] += g * yy[jj + t];
                    h4[jj] += g * xy[jj + t];
                }
            }
            *(float4*)&hb[0][r][j4] = make_float4(h0[0], h0[1], h0[2], h0[3]);
            *(float4*)&hb[1][r][j4] = make_float4(h1[0], h1[1], h1[2], h1[3]);
            *(float4*)&hb[2][r][j4] = make_float4(h2[0], h2[1], h2[2], h2[3]);
            *(float4*)&hb[3][r][j4] = make_float4(h3[0], h3[1], h3[2], h3[3]);
            *(float4*)&hb[4][r][j4] = make_float4(h4[0], h4[1], h4[2], h4[3]);
        }
        __syncthreads();   // hb(c) visible; sx/sy(c) readers (B) done

        // ---------- A(c+1) then C(c): disjoint LDS, shared barrier region ----------
        if (c < 2) stage_a(c + 1);   // HBM loads in flight under C's compute

        // ---------- Stage C: vertical conv + SSIM, 4 rows x 1 col per thread ----------
        {
            int j  = tid & 63;
            int i0 = (tid >> 6) * 4;
            float m1[4]  = {0,0,0,0}, m2[4]  = {0,0,0,0};
            float v11[4] = {0,0,0,0}, v22[4] = {0,0,0,0}, v12[4] = {0,0,0,0};
            #pragma unroll
            for (int t = 0; t < 14; ++t) {
                float b0 = hb[0][i0 + t][j];
                float b1 = hb[1][i0 + t][j];
                float b2 = hb[2][i0 + t][j];
                float b3 = hb[3][i0 + t][j];
                float b4 = hb[4][i0 + t][j];
                #pragma unroll
                for (int o = 0; o < 4; ++o) {
                    if (t - o >= 0 && t - o <= 10) {   // static after unroll
                        float g = gr[t - o];
                        m1[o]  += g * b0;
                        m2[o]  += g * b1;
                        v11[o] += g * b2;
                        v22[o] += g * b3;
                        v12[o] += g * b4;
                    }
                }
            }
            const float C1 = 0.0001f, C2 = 0.0009f;
            #pragma unroll
            for (int o = 0; o < 4; ++o) {
                int gy = y0 + i0 + o, gx = x0 + j;
                if (gy < H && gx < W) {
                    float mu1 = m1[o], mu2 = m2[o];
                    float mu11 = mu1 * mu1, mu22 = mu2 * mu2, mu12 = mu1 * mu2;
                    float s11 = v11[o] - mu11;
                    float s22 = v22[o] - mu22;
                    float s12 = v12[o] - mu12;
                    float num = (2.0f * mu12 + C1) * (2.0f * s12 + C2);
                    float den = (mu11 + mu22 + C1) * (s11 + s22 + C2);
                    acc += num / den;
                }
            }
        }
    }

    // ---------- block reduction + fused finalize ----------
    #pragma unroll
    for (int off = 32; off > 0; off >>= 1)
        acc += __shfl_down(acc, off, 64);
    int lane = tid & 63, wid = tid >> 6;
    if (lane == 0) wsum[wid] = acc;
    __syncthreads();
    if (tid == 0) {
        float bsum = wsum[0] + wsum[1] + wsum[2] + wsum[3]
                   + wsum[4] + wsum[5] + wsum[6] + wsum[7];
        atomicAdd(ws, bsum);
        __threadfence();
        unsigned done = atomicAdd((unsigned*)ws + 1, 1u);
        if (done == nblocks - 1) {          // last block: all adds visible
            __threadfence();
            float s = atomicAdd(ws, 0.0f);  // atomic read of full sum
            out[0] = 1.0f - s * inv_n;
        }
    }
}

extern "C" void kernel_launch(void* const* d_in, const int* in_sizes, int n_in,
                              void* d_out, int out_size, void* d_ws, size_t ws_size,
                              hipStream_t stream) {
    const float* img1   = (const float*)d_in[0];
    const float* img2   = (const float*)d_in[1];
    const float* window = (const float*)d_in[2];
    float* out = (float*)d_out;
    float* ws  = (float*)d_ws;

    // Assume square image: in_sizes[0] = H*W*3
    long hw = (long)in_sizes[0] / 3;
    int W = (int)(sqrt((double)hw) + 0.5);
    int H = (int)(hw / W);

    float inv_n = (float)(1.0 / ((double)H * (double)W * 3.0));

    dim3 grid((W + TILEW - 1) / TILEW, (H + TILEH - 1) / TILEH);
    unsigned nblocks = grid.x * grid.y;

    zero_kernel<<<1, 1, 0, stream>>>(ws);
    ssim_kernel<<<grid, 512, 0, stream>>>(img1, img2, window, ws, out,
                                          H, W, inv_n, nblocks);
}

// Round 15
// 206.552 us; speedup vs baseline: 1.1809x; 1.1809x over previous
//
#include <hip/hip_runtime.h>
#include <math.h>

#define TILEW 64
#define TILEH 32
#define HALO  5
#define IH    42     // TILEH + 2*HALO staged rows
#define SW    76     // sx/sy row stride (19*4; Stage-A writes wave-contiguous)
#define NG    19     // float4 col-groups per staged row
#define HBW   64     // hb row stride; Stage-C reads bank=j&31, 2-way (free)

__global__ void zero_kernel(float* ws) { ws[0] = 0.0f; }

__global__ void finalize_kernel(const float* ws, float* out, float inv_n) {
    out[0] = 1.0f - ws[0] * inv_n;
}

// FINAL (round 15) = round-9 kernel verbatim — the session's best verified
// configuration: kernel 123.4us, bench 206.8us (vs 216.1us entry).
// Converged structure and the measured evidence that closed each lever:
//  - 64x32 tile, 512 threads, 79KB LDS -> 2 blocks/CU, 16 waves/CU.
//    Occupancy capped by Stage B's ~100-128 VGPR live set: arg2>=5
//    spills (r1/r12), intra-block role split spills (r10), 8-row C
//    spills (r13). arg2=4 is the proven operating point.
//  - Stage A branchless ok?:0 (r4/r5: wave-uniform interior branch
//    serializes load batches; halves effective HBM BW).
//  - hb row-major [42][64] (r4: pair-packing -> 4-way bank conflict).
//  - barrier flow: sync; B; sync; A(c+1); C (6 barriers/block).
//  - separate finalize dispatch (r14's fused tail coincided with a ~33%
//    regression on a suspect container; unproven, not committed).
__global__ __launch_bounds__(512, 4) void ssim_kernel(
    const float* __restrict__ img1, const float* __restrict__ img2,
    const float* __restrict__ window, float* __restrict__ accum,
    int H, int W)
{
    __shared__ float sx[IH][SW];
    __shared__ float sy[IH][SW];
    __shared__ float hb[5][IH][HBW];
    __shared__ float wsum[8];

    const int tid = threadIdx.x;
    const int x0  = blockIdx.x * TILEW;
    const int y0  = blockIdx.y * TILEH;

    // Recover the separable 1D Gaussian from the 2D window:
    // w2d = outer(g,g) -> g[j] = w2d[5][j] / sqrt(w2d[5][5])
    float gr[11];
    {
        float inv = 1.0f / sqrtf(window[60]);     // window[5*11+5]
        #pragma unroll
        for (int t = 0; t < 11; ++t) gr[t] = window[55 + t] * inv;
    }

    // Stage A: load zero-padded input tile for channel c into sx/sy.
    // Branchless; loads feed LDS stores in the same body, nothing persists.
    auto stage_a = [&](int c) {
        for (int item = tid; item < IH * NG; item += 512) {
            int r   = item / NG;
            int j4  = (item % NG) * 4;
            int gh  = y0 + r - HALO;
            int gx0 = x0 + j4 - HALO;
            bool rowok = ((unsigned)gh < (unsigned)H);
            float vx[4], vy[4];
            #pragma unroll
            for (int k = 0; k < 4; ++k) {
                int gx = gx0 + k;
                bool ok = rowok && ((unsigned)gx < (unsigned)W);
                long off = ((long)gh * W + gx) * 3 + c;   // HWC layout
                vx[k] = ok ? img1[off] : 0.0f;
                vy[k] = ok ? img2[off] : 0.0f;
            }
            *(float4*)&sx[r][j4] = make_float4(vx[0], vx[1], vx[2], vx[3]);
            *(float4*)&sy[r][j4] = make_float4(vy[0], vy[1], vy[2], vy[3]);
        }
    };

    float acc = 0.0f;

    stage_a(0);   // prologue: channel 0

    for (int c = 0; c < 3; ++c) {
        __syncthreads();   // sx/sy(c) visible; hb readers of prev channel done

        // ---------- Stage B: horizontal conv (5 quantities), 4 cols/thread ----------
        for (int item = tid; item < IH * 16; item += 512) {
            int r  = item >> 4;
            int j4 = (item & 15) * 4;
            float xv[16], yv[16];
            *(float4*)&xv[0]  = *(const float4*)&sx[r][j4];
            *(float4*)&xv[4]  = *(const float4*)&sx[r][j4 + 4];
            *(float4*)&xv[8]  = *(const float4*)&sx[r][j4 + 8];
            *(float4*)&xv[12] = *(const float4*)&sx[r][j4 + 12];
            *(float4*)&yv[0]  = *(const float4*)&sy[r][j4];
            *(float4*)&yv[4]  = *(const float4*)&sy[r][j4 + 4];
            *(float4*)&yv[8]  = *(const float4*)&sy[r][j4 + 8];
            *(float4*)&yv[12] = *(const float4*)&sy[r][j4 + 12];

            float xx[14], yy[14], xy[14];
            #pragma unroll
            for (int t = 0; t < 14; ++t) {
                xx[t] = xv[t] * xv[t];
                yy[t] = yv[t] * yv[t];
                xy[t] = xv[t] * yv[t];
            }
            float h0[4] = {0,0,0,0}, h1[4] = {0,0,0,0}, h2[4] = {0,0,0,0};
            float h3[4] = {0,0,0,0}, h4[4] = {0,0,0,0};
            #pragma unroll
            for (int jj = 0; jj < 4; ++jj) {
                #pragma unroll
                for (int t = 0; t < 11; ++t) {
                    float g = gr[t];
                    h0[jj] += g * xv[jj + t];
                    h1[jj] += g * yv[jj + t];
                    h2[jj] += g * xx[jj + t];
                    h3[jj] += g * yy[jj + t];
                    h4[jj] += g * xy[jj + t];
                }
            }
            *(float4*)&hb[0][r][j4] = make_float4(h0[0], h0[1], h0[2], h0[3]);
            *(float4*)&hb[1][r][j4] = make_float4(h1[0], h1[1], h1[2], h1[3]);
            *(float4*)&hb[2][r][j4] = make_float4(h2[0], h2[1], h2[2], h2[3]);
            *(float4*)&hb[3][r][j4] = make_float4(h3[0], h3[1], h3[2], h3[3]);
            *(float4*)&hb[4][r][j4] = make_float4(h4[0], h4[1], h4[2], h4[3]);
        }
        __syncthreads();   // hb(c) visible; sx/sy(c) readers (B) done

        // ---------- A(c+1) then C(c): disjoint LDS, shared barrier region ----------
        if (c < 2) stage_a(c + 1);   // HBM loads in flight under C's compute

        // ---------- Stage C: vertical conv + SSIM, 4 rows x 1 col per thread ----------
        {
            int j  = tid & 63;
            int i0 = (tid >> 6) * 4;
            float m1[4]  = {0,0,0,0}, m2[4]  = {0,0,0,0};
            float v11[4] = {0,0,0,0}, v22[4] = {0,0,0,0}, v12[4] = {0,0,0,0};
            #pragma unroll
            for (int t = 0; t < 14; ++t) {
                float b0 = hb[0][i0 + t][j];
                float b1 = hb[1][i0 + t][j];
                float b2 = hb[2][i0 + t][j];
                float b3 = hb[3][i0 + t][j];
                float b4 = hb[4][i0 + t][j];
                #pragma unroll
                for (int o = 0; o < 4; ++o) {
                    if (t - o >= 0 && t - o <= 10) {   // static after unroll
                        float g = gr[t - o];
                        m1[o]  += g * b0;
                        m2[o]  += g * b1;
                        v11[o] += g * b2;
                        v22[o] += g * b3;
                        v12[o] += g * b4;
                    }
                }
            }
            const float C1 = 0.0001f, C2 = 0.0009f;
            #pragma unroll
            for (int o = 0; o < 4; ++o) {
                int gy = y0 + i0 + o, gx = x0 + j;
                if (gy < H && gx < W) {
                    float mu1 = m1[o], mu2 = m2[o];
                    float mu11 = mu1 * mu1, mu22 = mu2 * mu2, mu12 = mu1 * mu2;
                    float s11 = v11[o] - mu11;
                    float s22 = v22[o] - mu22;
                    float s12 = v12[o] - mu12;
                    float num = (2.0f * mu12 + C1) * (2.0f * s12 + C2);
                    float den = (mu11 + mu22 + C1) * (s11 + s22 + C2);
                    acc += num / den;
                }
            }
        }
    }

    // ---------- block reduction ----------
    #pragma unroll
    for (int off = 32; off > 0; off >>= 1)
        acc += __shfl_down(acc, off, 64);
    int lane = tid & 63, wid = tid >> 6;
    if (lane == 0) wsum[wid] = acc;
    __syncthreads();
    if (tid == 0) {
        float bsum = wsum[0] + wsum[1] + wsum[2] + wsum[3]
                   + wsum[4] + wsum[5] + wsum[6] + wsum[7];
        atomicAdd(accum, bsum);
    }
}

extern "C" void kernel_launch(void* const* d_in, const int* in_sizes, int n_in,
                              void* d_out, int out_size, void* d_ws, size_t ws_size,
                              hipStream_t stream) {
    const float* img1   = (const float*)d_in[0];
    const float* img2   = (const float*)d_in[1];
    const float* window = (const float*)d_in[2];
    float* out = (float*)d_out;
    float* ws  = (float*)d_ws;

    // Assume square image: in_sizes[0] = H*W*3
    long hw = (long)in_sizes[0] / 3;
    int W = (int)(sqrt((double)hw) + 0.5);
    int H = (int)(hw / W);

    float inv_n = (float)(1.0 / ((double)H * (double)W * 3.0));

    dim3 grid((W + TILEW - 1) / TILEW, (H + TILEH - 1) / TILEH);

    zero_kernel<<<1, 1, 0, stream>>>(ws);
    ssim_kernel<<<grid, 512, 0, stream>>>(img1, img2, window, ws, H, W);
    finalize_kernel<<<1, 1, 0, stream>>>(ws, out, inv_n);
}